// Round 6
// baseline (101.291 us; speedup 1.0000x reference)
//
#include <hip/hip_runtime.h>

// ConvAutoEncoder: B=16384, T=64, C=2, D=4
// out = [encoder_out (B*128 f32) | decoded (B*128 f32)]
// Fused kernel; attention uses DPP row-rotation (VALU) instead of LDS broadcast.

typedef __attribute__((ext_vector_type(8))) short bf16x8;
typedef __attribute__((ext_vector_type(4))) float f32x4;

__device__ __forceinline__ unsigned short f2bf(float f) {
    unsigned int u = __builtin_bit_cast(unsigned int, f);
    return (unsigned short)((u + 0x7FFFu + ((u >> 16) & 1u)) >> 16);
}
__device__ __forceinline__ unsigned int pack2bf(float a, float b) {
    return (unsigned int)f2bf(a) | ((unsigned int)f2bf(b) << 16);
}
// rotate within 16-lane DPP row by 1 (VALU pipe, no LDS)
__device__ __forceinline__ float dpp_ror1(float v) {
    int i = __builtin_bit_cast(int, v);
    i = __builtin_amdgcn_mov_dpp(i, 0x121, 0xF, 0xF, false);   // row_ror:1
    return __builtin_bit_cast(float, i);
}

#define SWZ(row) (((row) & 7) << 3)   // ushort-index XOR == byte XOR ((row&7)<<4)

// ---------------- kernel 0: weight prep ----------------
__global__ void k0_prep(const float* __restrict__ w1, const float* __restrict__ w2,
                        const float* __restrict__ cw, const float* __restrict__ cb,
                        unsigned short* __restrict__ w1b, unsigned short* __restrict__ w2b,
                        unsigned short* __restrict__ wcv, float* __restrict__ biasf) {
    int i = blockIdx.x * 256 + threadIdx.x;      // 0..65535
    if (i < 512 * 128) { w1b[i] = f2bf(w1[i]); w2b[i] = f2bf(w2[i]); }
    if (i < 128 * 256) {
        int f = i >> 8, kd = i & 255;            // f = 2*o + s, kd = node*4 + d
        int o = f >> 1, s = f & 1, node = kd >> 2, d = kd & 3;
        int k = d - s;
        float v = (k >= 0 && k < 3) ? cw[o * 192 + node * 3 + k] : 0.f;
        wcv[i] = f2bf(v);
    }
    if (i < 128) biasf[i] = cb[i >> 1];
}

// ---------------- fused kernel ----------------
// 8 waves, 16 batches/block. Attention: wave wv rows 2wv..2wv+1, DPP rotation.
// Conv: wave owns fb=wv. L1: nb=4wv..4wv+3. L2: mb=wv. Swizzled LDS between phases.
__global__ __launch_bounds__(512, 4) void k_fused(
    const float* __restrict__ x,             // (B,64,2)
    const float* __restrict__ W_gat,         // (4,2)
    const float* __restrict__ a_attn,        // (8,)
    const unsigned short* __restrict__ w1b,  // (512,128)
    const unsigned short* __restrict__ w2b,  // (128,512)
    const unsigned short* __restrict__ wcv,  // (128,256)
    const float* __restrict__ biasf,         // (128,)
    const float* __restrict__ b1,            // (512,)
    const float* __restrict__ b2,            // (128,)
    float* __restrict__ enc_out,             // (B,128) f32
    float* __restrict__ dec_out)             // (B,128) f32
{
    __shared__ unsigned short h_lds[16 * 256];     // bf16, swizzled, 8KB
    __shared__ unsigned short flat_lds[16 * 128];  // bf16, swizzled, 4KB
    __shared__ unsigned short hdec_lds[16 * 512];  // bf16, swizzled, 16KB

    const int tid = threadIdx.x, lane = tid & 63, wv = tid >> 6;  // wv 0..7
    const int r = lane & 15, g = lane >> 4;
    const int base = blockIdx.x * 16;

    // ================= attention (2 rows per wave, zero LDS scratch) =================
    {
        const float Wg00 = W_gat[0], Wg01 = W_gat[1], Wg10 = W_gat[2], Wg11 = W_gat[3];
        const float Wg20 = W_gat[4], Wg21 = W_gat[5], Wg30 = W_gat[6], Wg31 = W_gat[7];
        const float as0 = a_attn[0], as1 = a_attn[1], as2 = a_attn[2], as3 = a_attn[3];
        const float ad0 = a_attn[4], ad1 = a_attn[5], ad2 = a_attn[6], ad3 = a_attn[7];
        const float L2E = 1.4426950408889634f;
        const float SL = 0.2f;

        // prefetch both rows' x up front (independent HBM loads)
        const float2 xv0 = ((const float2*)x)[(size_t)(base + wv * 2 + 0) * 64 + lane];
        const float2 xv1 = ((const float2*)x)[(size_t)(base + wv * 2 + 1) * 64 + lane];

        #pragma unroll
        for (int t = 0; t < 2; ++t) {
            const int lr = wv * 2 + t;
            const float2 xv = t ? xv1 : xv0;

            const float z0 = xv.x * Wg00 + xv.y * Wg01;
            const float z1 = xv.x * Wg10 + xv.y * Wg11;
            const float z2 = xv.x * Wg20 + xv.y * Wg21;
            const float z3 = xv.x * Wg30 + xv.y * Wg31;
            const float es = z0 * as0 + z1 * as1 + z2 * as2 + z3 * as3;
            const float ed = z0 * ad0 + z1 * ad1 + z2 * ad2 + z3 * ad3;
            const float u = __builtin_amdgcn_exp2f(es * L2E);         // e^{es}
            const float v = __builtin_amdgcn_exp2f(es * (SL * L2E));  // e^{0.2 es}
            const float U = __builtin_amdgcn_exp2f(ed * L2E);
            const float V = __builtin_amdgcn_exp2f(ed * (SL * L2E));
            const float pS = fmaxf(u * U, v * V);                     // self term

            float r0 = z0, r1 = z1, r2 = z2, r3 = z3, r4 = u, r5 = v;
            float S = 0.f, H0 = 0.f, H1 = 0.f, H2 = 0.f, H3 = 0.f;

            // visit all 64 source lanes: 4 xor-groups x 16 row-rotations
            #pragma unroll
            for (int g4 = 0; g4 < 4; ++g4) {
                if (g4) {
                    const int m = (g4 == 2) ? 48 : 16;
                    r0 = __shfl_xor(r0, m); r1 = __shfl_xor(r1, m);
                    r2 = __shfl_xor(r2, m); r3 = __shfl_xor(r3, m);
                    r4 = __shfl_xor(r4, m); r5 = __shfl_xor(r5, m);
                }
                #pragma unroll
                for (int s = 0; s < 16; ++s) {
                    if (s) {
                        r0 = dpp_ror1(r0); r1 = dpp_ror1(r1); r2 = dpp_ror1(r2);
                        r3 = dpp_ror1(r3); r4 = dpp_ror1(r4); r5 = dpp_ror1(r5);
                    }
                    const float P = fmaxf(r4 * U, r5 * V);   // exp(lrelu(es_i+ed_j))
                    S += P;
                    H0 += P * r0; H1 += P * r1; H2 += P * r2; H3 += P * r3;
                }
            }
            // remove i==j self contribution (identical fp expression -> exact)
            const float rs = 1.0f / (S - pS);
            const float h0 = (H0 - pS * z0) * rs;
            const float h1 = (H1 - pS * z1) * rs;
            const float h2 = (H2 - pS * z2) * rs;
            const float h3 = (H3 - pS * z3) * rs;
            const int hidx = (lr * 256 + lane * 4) ^ SWZ(lr);
            *(uint2*)(&h_lds[hidx]) = make_uint2(pack2bf(h0, h1), pack2bf(h2, h3));
        }
    }
    __syncthreads();

    // ================= conv (as matmul, K=256), wave owns fb=wv =================
    f32x4 ca = (f32x4){0.f, 0.f, 0.f, 0.f};
    f32x4 cb2 = (f32x4){0.f, 0.f, 0.f, 0.f};
    #pragma unroll
    for (int kc = 0; kc < 4; ++kc) {
        const bf16x8 hf0 = *(const bf16x8*)(&h_lds[(r * 256 + kc * 32 + g * 8) ^ SWZ(r)]);
        const bf16x8 hf1 = *(const bf16x8*)(&h_lds[(r * 256 + (kc + 4) * 32 + g * 8) ^ SWZ(r)]);
        const bf16x8 wf0 = *(const bf16x8*)(wcv + (wv * 16 + r) * 256 + kc * 32 + g * 8);
        const bf16x8 wf1 = *(const bf16x8*)(wcv + (wv * 16 + r) * 256 + (kc + 4) * 32 + g * 8);
        ca  = __builtin_amdgcn_mfma_f32_16x16x32_bf16(wf0, hf0, ca, 0, 0, 0);
        cb2 = __builtin_amdgcn_mfma_f32_16x16x32_bf16(wf1, hf1, cb2, 0, 0, 0);
    }
    {
        const f32x4 cc = ca + cb2;
        const int f0 = wv * 16 + g * 4;
        const float4 bs = *(const float4*)(biasf + f0);
        const float v0 = cc[0] + bs.x, v1 = cc[1] + bs.y;
        const float v2 = cc[2] + bs.z, v3 = cc[3] + bs.w;
        *(float4*)(enc_out + (size_t)(base + r) * 128 + f0) = make_float4(v0, v1, v2, v3);
        const int fidx = (r * 128 + f0) ^ SWZ(r);
        *(uint2*)(&flat_lds[fidx]) = make_uint2(pack2bf(v0, v1), pack2bf(v2, v3));
    }
    __syncthreads();

    // ================= decoder layer1: 128 -> 512, relu; wave owns nb=4wv..4wv+3 =====
    bf16x8 ff1[4];
    #pragma unroll
    for (int kb = 0; kb < 4; ++kb)
        ff1[kb] = *(const bf16x8*)(&flat_lds[(r * 128 + kb * 32 + g * 8) ^ SWZ(r)]);
    #pragma unroll
    for (int t = 0; t < 4; ++t) {
        const int nb = wv * 4 + t;
        f32x4 a1 = (f32x4){0.f, 0.f, 0.f, 0.f};
        #pragma unroll
        for (int kb = 0; kb < 4; ++kb) {
            const bf16x8 wf = *(const bf16x8*)(w1b + (nb * 16 + r) * 128 + kb * 32 + g * 8);
            a1 = __builtin_amdgcn_mfma_f32_16x16x32_bf16(wf, ff1[kb], a1, 0, 0, 0);
        }
        const int n0 = nb * 16 + g * 4;
        const float4 bs = *(const float4*)(b1 + n0);
        const float v0 = fmaxf(a1[0] + bs.x, 0.f);
        const float v1 = fmaxf(a1[1] + bs.y, 0.f);
        const float v2 = fmaxf(a1[2] + bs.z, 0.f);
        const float v3 = fmaxf(a1[3] + bs.w, 0.f);
        const int hdidx = (r * 512 + n0) ^ SWZ(r);
        *(uint2*)(&hdec_lds[hdidx]) = make_uint2(pack2bf(v0, v1), pack2bf(v2, v3));
    }
    __syncthreads();

    // ================= decoder layer2: 512 -> 128; wave owns mb=wv =================
    f32x4 d2a = (f32x4){0.f, 0.f, 0.f, 0.f};
    f32x4 d2b = (f32x4){0.f, 0.f, 0.f, 0.f};
    #pragma unroll
    for (int np = 0; np < 8; ++np) {
        const bf16x8 h0 = *(const bf16x8*)(&hdec_lds[(r * 512 + np * 32 + g * 8) ^ SWZ(r)]);
        const bf16x8 h1 = *(const bf16x8*)(&hdec_lds[(r * 512 + (np + 8) * 32 + g * 8) ^ SWZ(r)]);
        const bf16x8 w0 = *(const bf16x8*)(w2b + (wv * 16 + r) * 512 + np * 32 + g * 8);
        const bf16x8 w1 = *(const bf16x8*)(w2b + (wv * 16 + r) * 512 + (np + 8) * 32 + g * 8);
        d2a = __builtin_amdgcn_mfma_f32_16x16x32_bf16(w0, h0, d2a, 0, 0, 0);
        d2b = __builtin_amdgcn_mfma_f32_16x16x32_bf16(w1, h1, d2b, 0, 0, 0);
    }
    {
        const f32x4 dd = d2a + d2b;
        const int m0 = wv * 16 + g * 4;
        const float4 bs = *(const float4*)(b2 + m0);
        *(float4*)(dec_out + (size_t)(base + r) * 128 + m0) =
            make_float4(dd[0] + bs.x, dd[1] + bs.y, dd[2] + bs.z, dd[3] + bs.w);
    }
}

extern "C" void kernel_launch(void* const* d_in, const int* in_sizes, int n_in,
                              void* d_out, int out_size, void* d_ws, size_t ws_size,
                              hipStream_t stream) {
    const float* x      = (const float*)d_in[0];
    const float* W_gat  = (const float*)d_in[1];
    const float* a_attn = (const float*)d_in[2];
    const float* conv_w = (const float*)d_in[3];
    const float* conv_b = (const float*)d_in[4];
    const float* dec_w1 = (const float*)d_in[5];
    const float* dec_b1 = (const float*)d_in[6];
    const float* dec_w2 = (const float*)d_in[7];
    const float* dec_b2 = (const float*)d_in[8];
    float* out = (float*)d_out;

    const int B = in_sizes[0] / 128;                 // 16384
    unsigned short* w1b = (unsigned short*)d_ws;     // 512*128
    unsigned short* w2b = w1b + 512 * 128;           // 128*512
    unsigned short* wcv = w2b + 128 * 512;           // 128*256
    float* biasf = (float*)(wcv + 128 * 256);        // 128

    k0_prep<<<256, 256, 0, stream>>>(dec_w1, dec_w2, conv_w, conv_b, w1b, w2b, wcv, biasf);

    k_fused<<<B / 16, 512, 0, stream>>>(x, W_gat, a_attn, w1b, w2b, wcv, biasf,
                                        dec_b1, dec_b2, out, out + (size_t)B * 128);
}

// Round 7
// 54.497 us; speedup vs baseline: 1.8586x; 1.8586x over previous
//
#include <hip/hip_runtime.h>

// ConvAutoEncoder: B=16384, T=64, C=2, D=4
// out = [encoder_out (B*128 f32) | decoded (B*128 f32)]
// Fused kernel (R4 structure): 4 waves / 16 batches per block.
// Attention reformulated: per-neighbor (x0,x1,u,v), accumulate (S, A0, A1), h = W·A/S.

typedef __attribute__((ext_vector_type(8))) short bf16x8;
typedef __attribute__((ext_vector_type(4))) float f32x4;

__device__ __forceinline__ unsigned short f2bf(float f) {
    unsigned int u = __builtin_bit_cast(unsigned int, f);
    return (unsigned short)((u + 0x7FFFu + ((u >> 16) & 1u)) >> 16);
}
__device__ __forceinline__ unsigned int pack2bf(float a, float b) {
    return (unsigned int)f2bf(a) | ((unsigned int)f2bf(b) << 16);
}

#define SWZ(row) (((row) & 7) << 3)   // ushort-index XOR == byte XOR ((row&7)<<4)

// ---------------- kernel 0: weight prep ----------------
__global__ void k0_prep(const float* __restrict__ w1, const float* __restrict__ w2,
                        const float* __restrict__ cw, const float* __restrict__ cb,
                        unsigned short* __restrict__ w1b, unsigned short* __restrict__ w2b,
                        unsigned short* __restrict__ wcv, float* __restrict__ biasf) {
    int i = blockIdx.x * 256 + threadIdx.x;      // 0..65535
    if (i < 512 * 128) { w1b[i] = f2bf(w1[i]); w2b[i] = f2bf(w2[i]); }
    if (i < 128 * 256) {
        int f = i >> 8, kd = i & 255;            // f = 2*o + s, kd = node*4 + d
        int o = f >> 1, s = f & 1, node = kd >> 2, d = kd & 3;
        int k = d - s;
        float v = (k >= 0 && k < 3) ? cw[o * 192 + node * 3 + k] : 0.f;
        wcv[i] = f2bf(v);
    }
    if (i < 128) biasf[i] = cb[i >> 1];
}

// ---------------- fused kernel ----------------
// 4 waves, 16 batches/block. Attention: wave wv rows 4wv..4wv+3, per-row LDS buffers,
// 2-row interleaved accumulation. Conv: fb={wv,wv+4}. L1: nb=8wv..8wv+7. L2: mb={wv,wv+4}.
__global__ __launch_bounds__(256, 4) void k_fused(
    const float* __restrict__ x,             // (B,64,2)
    const float* __restrict__ W_gat,         // (4,2)
    const float* __restrict__ a_attn,        // (8,)
    const unsigned short* __restrict__ w1b,  // (512,128)
    const unsigned short* __restrict__ w2b,  // (128,512)
    const unsigned short* __restrict__ wcv,  // (128,256)
    const float* __restrict__ biasf,         // (128,)
    const float* __restrict__ b1,            // (512,)
    const float* __restrict__ b2,            // (128,)
    float* __restrict__ enc_out,             // (B,128) f32
    float* __restrict__ dec_out)             // (B,128) f32
{
    __shared__ __align__(16) unsigned char smem[28672];
    unsigned short* h_lds    = (unsigned short*)smem;            // [16][256] bf16 swz, 8KB
    unsigned short* flat_lds = (unsigned short*)(smem + 8192);   // [16][128] bf16 swz, 4KB
    float*          scr      = (float*)(smem + 12288);           // [4 waves][4 rows][4][64], 16KB } aliased
    unsigned short* hdec_lds = (unsigned short*)(smem + 12288);  // [16][512] bf16 swz, 16KB      }

    const int tid = threadIdx.x, lane = tid & 63, wv = tid >> 6;  // wv 0..3
    const int r = lane & 15, g = lane >> 4;
    const int base = blockIdx.x * 16;

    // ================= attention (4 rows per wave) =================
    {
        const float Wg00 = W_gat[0], Wg01 = W_gat[1], Wg10 = W_gat[2], Wg11 = W_gat[3];
        const float Wg20 = W_gat[4], Wg21 = W_gat[5], Wg30 = W_gat[6], Wg31 = W_gat[7];
        const float as0 = a_attn[0], as1 = a_attn[1], as2 = a_attn[2], as3 = a_attn[3];
        const float ad0 = a_attn[4], ad1 = a_attn[5], ad2 = a_attn[6], ad3 = a_attn[7];
        // es = x0*cs0 + x1*cs1 ; ed = x0*cd0 + x1*cd1  (exact fold of z@a)
        const float cs0 = as0 * Wg00 + as1 * Wg10 + as2 * Wg20 + as3 * Wg30;
        const float cs1 = as0 * Wg01 + as1 * Wg11 + as2 * Wg21 + as3 * Wg31;
        const float cd0 = ad0 * Wg00 + ad1 * Wg10 + ad2 * Wg20 + ad3 * Wg30;
        const float cd1 = ad0 * Wg01 + ad1 * Wg11 + ad2 * Wg21 + ad3 * Wg31;
        const float L2E = 1.4426950408889634f;
        const float SL = 0.2f;

        float* wbuf = scr + wv * 1024;       // 4 rows x 256 floats (x0|x1|u|v)
        float x0s[4], x1s[4], us[4], vs[4], Us[4], Vs[4];

        #pragma unroll
        for (int t = 0; t < 4; ++t) {
            const float2 xv = ((const float2*)x)[(size_t)(base + wv * 4 + t) * 64 + lane];
            const float x0 = xv.x, x1 = xv.y;
            const float es = x0 * cs0 + x1 * cs1;
            const float ed = x0 * cd0 + x1 * cd1;
            const float u = __builtin_amdgcn_exp2f(es * L2E);         // e^{es}
            const float v = __builtin_amdgcn_exp2f(es * (SL * L2E));  // e^{0.2 es}
            const float U = __builtin_amdgcn_exp2f(ed * L2E);
            const float V = __builtin_amdgcn_exp2f(ed * (SL * L2E));
            float* Bf = wbuf + t * 256;
            Bf[lane] = x0; Bf[64 + lane] = x1; Bf[128 + lane] = u; Bf[192 + lane] = v;
            x0s[t] = x0; x1s[t] = x1; us[t] = u; vs[t] = v; Us[t] = U; Vs[t] = V;
        }

        #pragma unroll
        for (int tp = 0; tp < 2; ++tp) {      // two rows interleaved -> 2 independent streams
            const int ta = tp * 2, tb = ta + 1;
            const float* Ba = wbuf + ta * 256;
            const float* Bb = wbuf + tb * 256;
            const f32x4 Ua4 = {Us[ta], Us[ta], Us[ta], Us[ta]};
            const f32x4 Va4 = {Vs[ta], Vs[ta], Vs[ta], Vs[ta]};
            const f32x4 Ub4 = {Us[tb], Us[tb], Us[tb], Us[tb]};
            const f32x4 Vb4 = {Vs[tb], Vs[tb], Vs[tb], Vs[tb]};
            f32x4 Sa = {0.f, 0.f, 0.f, 0.f}, A0a = Sa, A1a = Sa;
            f32x4 Sb = Sa, A0b = Sa, A1b = Sa;
            #pragma unroll
            for (int i4 = 0; i4 < 16; ++i4) {
                const f32x4 ax0 = *(const f32x4*)(Ba + i4 * 4);
                const f32x4 ax1 = *(const f32x4*)(Ba + 64 + i4 * 4);
                const f32x4 au  = *(const f32x4*)(Ba + 128 + i4 * 4);
                const f32x4 av  = *(const f32x4*)(Ba + 192 + i4 * 4);
                const f32x4 bx0 = *(const f32x4*)(Bb + i4 * 4);
                const f32x4 bx1 = *(const f32x4*)(Bb + 64 + i4 * 4);
                const f32x4 bu  = *(const f32x4*)(Bb + 128 + i4 * 4);
                const f32x4 bv  = *(const f32x4*)(Bb + 192 + i4 * 4);
                const f32x4 Pa = __builtin_elementwise_max(au * Ua4, av * Va4);
                const f32x4 Pb = __builtin_elementwise_max(bu * Ub4, bv * Vb4);
                Sa += Pa; A0a += Pa * ax0; A1a += Pa * ax1;
                Sb += Pb; A0b += Pb * bx0; A1b += Pb * bx1;
            }
            #pragma unroll
            for (int q = 0; q < 2; ++q) {
                const int t = ta + q;
                const f32x4 S4  = q ? Sb : Sa;
                const f32x4 A04 = q ? A0b : A0a;
                const f32x4 A14 = q ? A1b : A1a;
                const float pS = fmaxf(us[t] * Us[t], vs[t] * Vs[t]);   // self term, exact
                const float S  = (S4[0] + S4[1]) + (S4[2] + S4[3]) - pS;
                const float A0 = (A04[0] + A04[1]) + (A04[2] + A04[3]) - pS * x0s[t];
                const float A1 = (A14[0] + A14[1]) + (A14[2] + A14[3]) - pS * x1s[t];
                const float rs = 1.0f / S;
                const float h0 = (Wg00 * A0 + Wg01 * A1) * rs;
                const float h1 = (Wg10 * A0 + Wg11 * A1) * rs;
                const float h2 = (Wg20 * A0 + Wg21 * A1) * rs;
                const float h3 = (Wg30 * A0 + Wg31 * A1) * rs;
                const int lr = wv * 4 + t;
                const int hidx = (lr * 256 + lane * 4) ^ SWZ(lr);
                *(uint2*)(&h_lds[hidx]) = make_uint2(pack2bf(h0, h1), pack2bf(h2, h3));
            }
        }
    }
    __syncthreads();

    // ================= conv (as matmul, K=256): fb = wv, wv+4 =================
    f32x4 accc[2];
    accc[0] = (f32x4){0.f, 0.f, 0.f, 0.f};
    accc[1] = (f32x4){0.f, 0.f, 0.f, 0.f};
    #pragma unroll
    for (int kc = 0; kc < 8; ++kc) {
        const bf16x8 hf  = *(const bf16x8*)(&h_lds[(r * 256 + kc * 32 + g * 8) ^ SWZ(r)]);
        const bf16x8 wfa = *(const bf16x8*)(wcv + (wv * 16 + r) * 256 + kc * 32 + g * 8);
        const bf16x8 wfb = *(const bf16x8*)(wcv + ((wv + 4) * 16 + r) * 256 + kc * 32 + g * 8);
        accc[0] = __builtin_amdgcn_mfma_f32_16x16x32_bf16(wfa, hf, accc[0], 0, 0, 0);
        accc[1] = __builtin_amdgcn_mfma_f32_16x16x32_bf16(wfb, hf, accc[1], 0, 0, 0);
    }
    #pragma unroll
    for (int q = 0; q < 2; ++q) {
        const int f0 = (wv + q * 4) * 16 + g * 4;
        const float4 bs = *(const float4*)(biasf + f0);
        const float v0 = accc[q][0] + bs.x, v1 = accc[q][1] + bs.y;
        const float v2 = accc[q][2] + bs.z, v3 = accc[q][3] + bs.w;
        *(float4*)(enc_out + (size_t)(base + r) * 128 + f0) = make_float4(v0, v1, v2, v3);
        const int fidx = (r * 128 + f0) ^ SWZ(r);
        *(uint2*)(&flat_lds[fidx]) = make_uint2(pack2bf(v0, v1), pack2bf(v2, v3));
    }
    __syncthreads();

    // ================= decoder layer1: 128 -> 512, relu; nb = 8wv..8wv+7 =================
    bf16x8 ff1[4];
    #pragma unroll
    for (int kb = 0; kb < 4; ++kb)
        ff1[kb] = *(const bf16x8*)(&flat_lds[(r * 128 + kb * 32 + g * 8) ^ SWZ(r)]);
    #pragma unroll
    for (int t = 0; t < 8; ++t) {
        const int nb = wv * 8 + t;
        f32x4 a1 = (f32x4){0.f, 0.f, 0.f, 0.f};
        #pragma unroll
        for (int kb = 0; kb < 4; ++kb) {
            const bf16x8 wf = *(const bf16x8*)(w1b + (nb * 16 + r) * 128 + kb * 32 + g * 8);
            a1 = __builtin_amdgcn_mfma_f32_16x16x32_bf16(wf, ff1[kb], a1, 0, 0, 0);
        }
        const int n0 = nb * 16 + g * 4;
        const float4 bs = *(const float4*)(b1 + n0);
        const float v0 = fmaxf(a1[0] + bs.x, 0.f);
        const float v1 = fmaxf(a1[1] + bs.y, 0.f);
        const float v2 = fmaxf(a1[2] + bs.z, 0.f);
        const float v3 = fmaxf(a1[3] + bs.w, 0.f);
        const int hdidx = (r * 512 + n0) ^ SWZ(r);
        *(uint2*)(&hdec_lds[hdidx]) = make_uint2(pack2bf(v0, v1), pack2bf(v2, v3));
    }
    __syncthreads();

    // ================= decoder layer2: 512 -> 128; mb = wv, wv+4 =================
    f32x4 acc2[2];
    acc2[0] = (f32x4){0.f, 0.f, 0.f, 0.f};
    acc2[1] = (f32x4){0.f, 0.f, 0.f, 0.f};
    #pragma unroll
    for (int np = 0; np < 16; ++np) {
        const bf16x8 hfd = *(const bf16x8*)(&hdec_lds[(r * 512 + np * 32 + g * 8) ^ SWZ(r)]);
        const bf16x8 wfa = *(const bf16x8*)(w2b + (wv * 16 + r) * 512 + np * 32 + g * 8);
        const bf16x8 wfb = *(const bf16x8*)(w2b + ((wv + 4) * 16 + r) * 512 + np * 32 + g * 8);
        acc2[0] = __builtin_amdgcn_mfma_f32_16x16x32_bf16(wfa, hfd, acc2[0], 0, 0, 0);
        acc2[1] = __builtin_amdgcn_mfma_f32_16x16x32_bf16(wfb, hfd, acc2[1], 0, 0, 0);
    }
    #pragma unroll
    for (int q = 0; q < 2; ++q) {
        const int m0 = (wv + q * 4) * 16 + g * 4;
        const float4 bs = *(const float4*)(b2 + m0);
        *(float4*)(dec_out + (size_t)(base + r) * 128 + m0) =
            make_float4(acc2[q][0] + bs.x, acc2[q][1] + bs.y,
                        acc2[q][2] + bs.z, acc2[q][3] + bs.w);
    }
}

extern "C" void kernel_launch(void* const* d_in, const int* in_sizes, int n_in,
                              void* d_out, int out_size, void* d_ws, size_t ws_size,
                              hipStream_t stream) {
    const float* x      = (const float*)d_in[0];
    const float* W_gat  = (const float*)d_in[1];
    const float* a_attn = (const float*)d_in[2];
    const float* conv_w = (const float*)d_in[3];
    const float* conv_b = (const float*)d_in[4];
    const float* dec_w1 = (const float*)d_in[5];
    const float* dec_b1 = (const float*)d_in[6];
    const float* dec_w2 = (const float*)d_in[7];
    const float* dec_b2 = (const float*)d_in[8];
    float* out = (float*)d_out;

    const int B = in_sizes[0] / 128;                 // 16384
    unsigned short* w1b = (unsigned short*)d_ws;     // 512*128
    unsigned short* w2b = w1b + 512 * 128;           // 128*512
    unsigned short* wcv = w2b + 128 * 512;           // 128*256
    float* biasf = (float*)(wcv + 128 * 256);        // 128

    k0_prep<<<256, 256, 0, stream>>>(dec_w1, dec_w2, conv_w, conv_b, w1b, w2b, wcv, biasf);

    k_fused<<<B / 16, 256, 0, stream>>>(x, W_gat, a_attn, w1b, w2b, wcv, biasf,
                                        dec_b1, dec_b2, out, out + (size_t)B * 128);
}